// Round 7
// baseline (302.868 us; speedup 1.0000x reference)
//
#include <hip/hip_runtime.h>
#include <cmath>

typedef __bf16 bf16x8 __attribute__((ext_vector_type(8)));
typedef float  f32x4  __attribute__((ext_vector_type(4)));
typedef float  f32x16 __attribute__((ext_vector_type(16)));

#define MFMA(a, b, c)   __builtin_amdgcn_mfma_f32_16x16x32_bf16((a), (b), (c), 0, 0, 0)
#define MFMA32(a, b, c) __builtin_amdgcn_mfma_f32_32x32x16_bf16((a), (b), (c), 0, 0, 0)

static __device__ __forceinline__ __bf16 f2bf(float f) {
  union { float f; unsigned u; } v; v.f = f;
  unsigned r = v.u + 0x7fffu + ((v.u >> 16) & 1u);
  union { unsigned short u; __bf16 b; } o; o.u = (unsigned short)(r >> 16);
  return o.b;
}
// truncating convert (1 VALU op) — used only for the attention P tile
static __device__ __forceinline__ __bf16 f2bf_tr(float f) {
  union { float f; unsigned u; } v; v.f = f;
  union { unsigned short u; __bf16 b; } o; o.u = (unsigned short)(v.u >> 16);
  return o.b;
}

typedef const __attribute__((address_space(1))) void* gas_t;
typedef __attribute__((address_space(3))) void* las_t;
static __device__ __forceinline__ void load_lds16(const __bf16* g, __bf16* l) {
  __builtin_amdgcn_global_load_lds((gas_t)g, (las_t)l, 16, 0, 0);
}

// ---------------- all weight transposes fp32[K][N] -> bf16[N][K], one launch ----------------
__global__ __launch_bounds__(256) void k_transpose_all(
    const float* __restrict__ Wq, const float* __restrict__ Wk,
    const float* __restrict__ Wv, const float* __restrict__ Wo,
    const float* __restrict__ W1, const float* __restrict__ W2,
    __bf16* __restrict__ wqkv, __bf16* __restrict__ wo,
    __bf16* __restrict__ w1t, __bf16* __restrict__ w2t) {
  int idx = blockIdx.x * 256 + threadIdx.x;  // [0, 3145728)
  const float* src; __bf16* dst; int off, logK, N;
  if (idx < 1048576) {
    int which = idx >> 18; off = idx & 262143; logK = 9; N = 512;
    src = which == 0 ? Wq : which == 1 ? Wk : which == 2 ? Wv : Wo;
    dst = which < 3 ? wqkv + which * 262144 : wo;
  } else if (idx < 2097152) {
    off = idx - 1048576; logK = 9; N = 2048; src = W1; dst = w1t;
  } else {
    off = idx - 2097152; logK = 11; N = 512; src = W2; dst = w2t;
  }
  int n = off >> logK, k = off & ((1 << logK) - 1);
  dst[off] = f2bf(src[(size_t)k * N + n]);
}

// ---------------- LN + RoPE (full-dim rope, half=256) -> h bf16 ----------------
__global__ __launch_bounds__(256) void k_ln_rope(const float* __restrict__ x,
                                                 const float* __restrict__ g,
                                                 const float* __restrict__ b,
                                                 __bf16* __restrict__ h) {
  int n = blockIdx.x, tid = threadIdx.x;
  const float* row = x + (size_t)n * 512;
  float v1 = row[tid], v2 = row[tid + 256];
  float s = v1 + v2, ss = v1 * v1 + v2 * v2;
  #pragma unroll
  for (int off = 1; off < 64; off <<= 1) { s += __shfl_xor(s, off, 64); ss += __shfl_xor(ss, off, 64); }
  __shared__ float red[2][4];
  if ((tid & 63) == 0) { red[0][tid >> 6] = s; red[1][tid >> 6] = ss; }
  __syncthreads();
  s  = red[0][0] + red[0][1] + red[0][2] + red[0][3];
  ss = red[1][0] + red[1][1] + red[1][2] + red[1][3];
  float mu = s * (1.f / 512.f);
  float var = ss * (1.f / 512.f) - mu * mu;
  float rs = rsqrtf(var + 1e-5f);
  float y1 = (v1 - mu) * rs * g[tid] + b[tid];
  float y2 = (v2 - mu) * rs * g[tid + 256] + b[tid + 256];
  int t = n & 2047;
  float inv = __expf(-(float)tid * 0.03597789207803197f);
  float ang = (float)t * inv;
  float sn, c;
  __sincosf(ang, &sn, &c);
  h[(size_t)n * 512 + tid]       = f2bf(y1 * c - y2 * sn);
  h[(size_t)n * 512 + tid + 256] = f2bf(y1 * sn + y2 * c);
}

// ---------------- 128x128 block GEMM, 4 waves (64x64 each), BK=64, swizzled LDS ----------------
// LDS: 128 rows x 8 chunks of 8 bf16; slot s of row r holds global k-chunk s^(r&7).
// Staging: wave w covers rows [w*32, w*32+32); lane's global chunk sg=(lane&7)^(lane>>3)
// is invariant across the 4 calls (row += 8 keeps row&7 = lane>>3).
template <int K>
static __device__ __forceinline__ void gemm128(const __bf16* __restrict__ A,
                                               const __bf16* __restrict__ Bt,
                                               f32x4 (&acc)[4][4]) {
  __shared__ __bf16 lA[128 * 64];
  __shared__ __bf16 lB[128 * 64];
  int bm = blockIdx.x & 63, bn = blockIdx.x >> 6;
  int tid = threadIdx.x, w = tid >> 6, lane = tid & 63;
  int l16 = lane & 15, quad = lane >> 4;
  int wr = (w >> 1) * 64, wc = (w & 1) * 64;
  int sg = (lane & 7) ^ (lane >> 3);
  const __bf16* ga = A  + (size_t)(bm * 128 + w * 32 + (lane >> 3)) * K + sg * 8;
  const __bf16* gb = Bt + (size_t)(bn * 128 + w * 32 + (lane >> 3)) * K + sg * 8;
  __bf16* saw = lA + w * 2048;
  __bf16* sbw = lB + w * 2048;
  #pragma unroll
  for (int i = 0; i < 4; ++i)
    #pragma unroll
    for (int j = 0; j < 4; ++j) acc[i][j] = {0.f, 0.f, 0.f, 0.f};
  for (int k0 = 0; k0 < K; k0 += 64) {
    #pragma unroll
    for (int c = 0; c < 4; ++c) {
      load_lds16(ga + k0 + (size_t)c * 8 * K, saw + c * 512);
      load_lds16(gb + k0 + (size_t)c * 8 * K, sbw + c * 512);
    }
    __syncthreads();
    #pragma unroll
    for (int kk = 0; kk < 2; ++kk) {
      int gg = kk * 4 + quad;
      bf16x8 af[4], bfr[4];
      #pragma unroll
      for (int i = 0; i < 4; ++i) {
        int row = wr + i * 16 + l16;
        __builtin_memcpy(&af[i], &lA[row * 64 + ((gg ^ (row & 7)) * 8)], 16);
      }
      #pragma unroll
      for (int j = 0; j < 4; ++j) {
        int row = wc + j * 16 + l16;
        __builtin_memcpy(&bfr[j], &lB[row * 64 + ((gg ^ (row & 7)) * 8)], 16);
      }
      #pragma unroll
      for (int i = 0; i < 4; ++i)
        #pragma unroll
        for (int j = 0; j < 4; ++j) acc[i][j] = MFMA(af[i], bfr[j], acc[i][j]);
    }
    __syncthreads();
  }
}

#define G128_EPILOG_IDX                                 \
  int bm = blockIdx.x & 63, bn = blockIdx.x >> 6;       \
  int lane = threadIdx.x & 63, w = threadIdx.x >> 6;    \
  int l16 = lane & 15, quad = lane >> 4;                \
  int wr = (w >> 1) * 64, wc = (w & 1) * 64;

// ---------------- QKV GEMM: h[8192][512] @ Wqkv_t[1536][512] ----------------
__global__ __launch_bounds__(256) void k_gemm_qkv(const __bf16* __restrict__ A,
                                                  const __bf16* __restrict__ Bt,
                                                  const float* __restrict__ bq,
                                                  const float* __restrict__ bk,
                                                  const float* __restrict__ bv,
                                                  __bf16* __restrict__ qo,
                                                  __bf16* __restrict__ ko,
                                                  __bf16* __restrict__ vT) {
  f32x4 acc[4][4];
  gemm128<512>(A, Bt, acc);
  G128_EPILOG_IDX
  int proj = bn >> 2;
  const float* bias = proj == 0 ? bq : (proj == 1 ? bk : bv);
  float scale = proj == 0 ? 0.125f : 1.f;  // fold 1/sqrt(DH) into q
  if (proj < 2) {
    __bf16* dst = proj == 0 ? qo : ko;
    #pragma unroll
    for (int i = 0; i < 4; ++i)
      #pragma unroll
      for (int j = 0; j < 4; ++j)
        #pragma unroll
        for (int r = 0; r < 4; ++r) {
          int c = (bn * 128 + wc + j * 16 + l16) & 511;
          int m = bm * 128 + wr + i * 16 + quad * 4 + r;
          int bI = m >> 11, t = m & 2047;
          int head = c >> 6, dh = c & 63;
          dst[(((size_t)bI * 8 + head) * 2048 + t) * 64 + dh] = f2bf((acc[i][j][r] + bias[c]) * scale);
        }
  } else {
    #pragma unroll
    for (int i = 0; i < 4; ++i)
      #pragma unroll
      for (int j = 0; j < 4; ++j)
        #pragma unroll
        for (int r = 0; r < 4; ++r) {
          int c = (bn * 128 + wc + j * 16 + l16) & 511;
          int m = bm * 128 + wr + i * 16 + quad * 4 + r;
          int bI = m >> 11, t = m & 2047;
          int head = c >> 6, dh = c & 63;
          vT[(((size_t)bI * 8 + head) * 64 + dh) * 2048 + t] = f2bf(acc[i][j][r] + bias[c]);
        }
  }
}

// ---------------- attention: 64-key iterations, all waves compute, swizzled LDS ----------------
__global__ __launch_bounds__(512) void k_attn(const __bf16* __restrict__ q,
                                              const __bf16* __restrict__ k,
                                              const __bf16* __restrict__ vT,
                                              __bf16* __restrict__ o) {
  __shared__ __align__(16) __bf16 Kt[64 * 64];
  __shared__ __align__(16) __bf16 Vt[64 * 64];
  __shared__ __align__(16) __bf16 P[8][32][40];   // per-wave 32x32 P, row stride 40
  __shared__ float cbuf[4][64][17];               // split-K combine
  int bh = blockIdx.x >> 4, qblk = blockIdx.x & 15;
  int tid = threadIdx.x, w = tid >> 6, lane = tid & 63;
  int l32 = lane & 31, h32 = lane >> 5;
  int qw = w & 3, half = w >> 2, hoff = half * 32;
  int qB = qblk * 128;
  int q0 = qB + qw * 32;
  const __bf16* qb = q + (size_t)bh * 2048 * 64;
  const __bf16* kb = k + (size_t)bh * 2048 * 64;
  const __bf16* vb = vT + (size_t)bh * 64 * 2048;
  bf16x8 aq[4];
  #pragma unroll
  for (int i = 0; i < 4; ++i)
    aq[i] = *(const bf16x8*)(qb + (size_t)(q0 + l32) * 64 + i * 16 + h32 * 8);
  f32x16 on0 = {0,0,0,0,0,0,0,0,0,0,0,0,0,0,0,0};
  f32x16 on1 = {0,0,0,0,0,0,0,0,0,0,0,0,0,0,0,0};
  float lsum[16];
  #pragma unroll
  for (int i = 0; i < 16; ++i) lsum[i] = 0.f;
  int srow = w * 8 + (lane >> 3);           // 0..63
  int sg = (lane & 7) ^ (srow & 7);
  const __bf16* gk = kb + (size_t)srow * 64 + sg * 8;
  const __bf16* gv = vb + (size_t)srow * 2048 + sg * 8;
  __bf16* skw = Kt + w * 512;
  __bf16* svw = Vt + w * 512;

  for (int it = 0; it < 32; ++it) {
    int kt64 = it * 64;
    if ((unsigned)(kt64 - qB) <= 64u) continue;  // fully banned for whole block
    load_lds16(gk + (size_t)kt64 * 64, skw);
    load_lds16(gv + kt64, svw);
    __syncthreads();
    int myk0 = kt64 + hoff;
    bool skip = (q0 + 31 - myk0 <= 128) && (myk0 + 31 - q0 <= 128);
    if (!skip) {
      bool need_mask = !((myk0 >= q0 + 160) || (myk0 <= q0 - 160));
      f32x16 sc = {0,0,0,0,0,0,0,0,0,0,0,0,0,0,0,0};
      int krow = hoff + l32;
      #pragma unroll
      for (int i = 0; i < 4; ++i) {
        int gg = i * 2 + h32;
        bf16x8 bk;
        __builtin_memcpy(&bk, &Kt[krow * 64 + ((gg ^ (l32 & 7)) * 8)], 16);
        sc = MFMA32(aq[i], bk, sc);
      }
      #pragma unroll
      for (int reg = 0; reg < 16; ++reg) {
        int row = (reg & 3) + 8 * (reg >> 2) + 4 * h32;
        float p = __expf(sc[reg]);   // scores pre-scaled by 1/8 via q; no max-shift needed
        if (need_mask) {
          int qi = q0 + row, kj = myk0 + l32;
          if ((unsigned)(qi - kj + 128) <= 256u) p = 0.f;
        }
        P[w][row][l32] = f2bf_tr(p);
        lsum[reg] += p;
      }
      bf16x8 ap0, ap1;
      __builtin_memcpy(&ap0, &P[w][l32][h32 * 8], 16);
      __builtin_memcpy(&ap1, &P[w][l32][16 + h32 * 8], 16);
      #pragma unroll
      for (int kk = 0; kk < 2; ++kk) {
        bf16x8 ap = kk ? ap1 : ap0;
        int gg = half * 4 + kk * 2 + h32;
        bf16x8 bv0, bv1;
        __builtin_memcpy(&bv0, &Vt[l32 * 64 + ((gg ^ (l32 & 7)) * 8)], 16);
        __builtin_memcpy(&bv1, &Vt[(32 + l32) * 64 + ((gg ^ (l32 & 7)) * 8)], 16);
        on0 = MFMA32(ap, bv0, on0);
        on1 = MFMA32(ap, bv1, on1);
      }
    }
    __syncthreads();
  }
  // -------- split-K combine (3 phases through cbuf) --------
  if (half) {
    for (int i = 0; i < 16; ++i) cbuf[qw][lane][i] = on0[i];
  }
  __syncthreads();
  if (!half) {
    for (int i = 0; i < 16; ++i) on0[i] += cbuf[qw][lane][i];
  }
  __syncthreads();
  if (half) {
    for (int i = 0; i < 16; ++i) cbuf[qw][lane][i] = on1[i];
  }
  __syncthreads();
  if (!half) {
    for (int i = 0; i < 16; ++i) on1[i] += cbuf[qw][lane][i];
  }
  __syncthreads();
  if (half) {
    for (int i = 0; i < 16; ++i) cbuf[qw][lane][i] = lsum[i];
  }
  __syncthreads();
  if (!half) {
    #pragma unroll
    for (int i = 0; i < 16; ++i) {
      float s = lsum[i] + cbuf[qw][lane][i];
      #pragma unroll
      for (int off = 1; off < 32; off <<= 1) s += __shfl_xor(s, off, 64);
      lsum[i] = 1.f / s;
    }
    int bI = bh >> 3, head = bh & 7;
    #pragma unroll
    for (int reg = 0; reg < 16; ++reg) {
      int row = (reg & 3) + 8 * (reg >> 2) + 4 * h32;
      size_t base = ((size_t)(bI * 2048 + q0 + row)) * 512 + head * 64;
      o[base + l32]      = f2bf(on0[reg] * lsum[reg]);
      o[base + 32 + l32] = f2bf(on1[reg] * lsum[reg]);
    }
  }
}

// ---------------- O-proj + residual: x2 = x + o@Wo + bo (fp32 out) ----------------
__global__ __launch_bounds__(256) void k_gemm_oproj(const __bf16* __restrict__ A,
                                                    const __bf16* __restrict__ Bt,
                                                    const float* __restrict__ bo,
                                                    const float* __restrict__ xin,
                                                    float* __restrict__ x2) {
  f32x4 acc[4][4];
  gemm128<512>(A, Bt, acc);
  G128_EPILOG_IDX
  #pragma unroll
  for (int i = 0; i < 4; ++i)
    #pragma unroll
    for (int j = 0; j < 4; ++j)
      #pragma unroll
      for (int r = 0; r < 4; ++r) {
        int n = bn * 128 + wc + j * 16 + l16;
        int m = bm * 128 + wr + i * 16 + quad * 4 + r;
        size_t idx = (size_t)m * 512 + n;
        x2[idx] = xin[idx] + acc[i][j][r] + bo[n];
      }
}

// ---------------- double layernorm -> f bf16 ----------------
__global__ __launch_bounds__(256) void k_ln_ln(const float* __restrict__ x2,
                                               const float* __restrict__ g1v,
                                               const float* __restrict__ b1v,
                                               const float* __restrict__ g2v,
                                               const float* __restrict__ b2v,
                                               __bf16* __restrict__ fout) {
  int n = blockIdx.x, tid = threadIdx.x;
  const float* row = x2 + (size_t)n * 512;
  float v1 = row[tid], v2 = row[tid + 256];
  __shared__ float red[2][4];
  float s = v1 + v2, ss = v1 * v1 + v2 * v2;
  #pragma unroll
  for (int off = 1; off < 64; off <<= 1) { s += __shfl_xor(s, off, 64); ss += __shfl_xor(ss, off, 64); }
  if ((tid & 63) == 0) { red[0][tid >> 6] = s; red[1][tid >> 6] = ss; }
  __syncthreads();
  s  = red[0][0] + red[0][1] + red[0][2] + red[0][3];
  ss = red[1][0] + red[1][1] + red[1][2] + red[1][3];
  float mu = s * (1.f / 512.f), var = ss * (1.f / 512.f) - mu * mu;
  float rs = rsqrtf(var + 1e-5f);
  float y1 = (v1 - mu) * rs * g1v[tid] + b1v[tid];
  float y2 = (v2 - mu) * rs * g1v[tid + 256] + b1v[tid + 256];
  __syncthreads();
  s = y1 + y2; ss = y1 * y1 + y2 * y2;
  #pragma unroll
  for (int off = 1; off < 64; off <<= 1) { s += __shfl_xor(s, off, 64); ss += __shfl_xor(ss, off, 64); }
  if ((tid & 63) == 0) { red[0][tid >> 6] = s; red[1][tid >> 6] = ss; }
  __syncthreads();
  s  = red[0][0] + red[0][1] + red[0][2] + red[0][3];
  ss = red[1][0] + red[1][1] + red[1][2] + red[1][3];
  float mu2 = s * (1.f / 512.f), var2 = ss * (1.f / 512.f) - mu2 * mu2;
  float rs2 = rsqrtf(var2 + 1e-5f);
  fout[(size_t)n * 512 + tid]       = f2bf((y1 - mu2) * rs2 * g2v[tid] + b2v[tid]);
  fout[(size_t)n * 512 + tid + 256] = f2bf((y2 - mu2) * rs2 * g2v[tid + 256] + b2v[tid + 256]);
}

// ---------------- FFN1 + exact GELU -> g1 bf16 ----------------
__global__ __launch_bounds__(256) void k_gemm_ffn1(const __bf16* __restrict__ A,
                                                   const __bf16* __restrict__ Bt,
                                                   const float* __restrict__ b1,
                                                   __bf16* __restrict__ g1) {
  f32x4 acc[4][4];
  gemm128<512>(A, Bt, acc);
  G128_EPILOG_IDX
  #pragma unroll
  for (int i = 0; i < 4; ++i)
    #pragma unroll
    for (int j = 0; j < 4; ++j)
      #pragma unroll
      for (int r = 0; r < 4; ++r) {
        int n = bn * 128 + wc + j * 16 + l16;
        int m = bm * 128 + wr + i * 16 + quad * 4 + r;
        float t = acc[i][j][r] + b1[n];
        float ge = 0.5f * t * (1.f + erff(t * 0.7071067811865475f));
        g1[(size_t)m * 2048 + n] = f2bf(ge);
      }
}

// ---------------- FFN2 + final residual -> out fp32 ----------------
__global__ __launch_bounds__(256) void k_gemm_ffn2(const __bf16* __restrict__ A,
                                                   const __bf16* __restrict__ Bt,
                                                   const float* __restrict__ b2,
                                                   const float* __restrict__ x2,
                                                   float* __restrict__ out) {
  f32x4 acc[4][4];
  gemm128<2048>(A, Bt, acc);
  G128_EPILOG_IDX
  #pragma unroll
  for (int i = 0; i < 4; ++i)
    #pragma unroll
    for (int j = 0; j < 4; ++j)
      #pragma unroll
      for (int r = 0; r < 4; ++r) {
        int n = bn * 128 + wc + j * 16 + l16;
        int m = bm * 128 + wr + i * 16 + quad * 4 + r;
        size_t idx = (size_t)m * 512 + n;
        out[idx] = x2[idx] + acc[i][j][r] + b2[n];
      }
}

extern "C" void kernel_launch(void* const* d_in, const int* in_sizes, int n_in,
                              void* d_out, int out_size, void* d_ws, size_t ws_size,
                              hipStream_t stream) {
  (void)in_sizes; (void)n_in; (void)out_size; (void)ws_size;
  const float* x   = (const float*)d_in[0];
  const float* Wq  = (const float*)d_in[1];
  const float* bq  = (const float*)d_in[2];
  const float* Wk  = (const float*)d_in[3];
  const float* bk  = (const float*)d_in[4];
  const float* Wv  = (const float*)d_in[5];
  const float* bv  = (const float*)d_in[6];
  const float* Wo  = (const float*)d_in[7];
  const float* bo  = (const float*)d_in[8];
  const float* lng = (const float*)d_in[9];
  const float* lnb = (const float*)d_in[10];
  const float* ffg = (const float*)d_in[11];
  const float* ffb = (const float*)d_in[12];
  const float* W1  = (const float*)d_in[13];
  const float* b1  = (const float*)d_in[14];
  const float* W2  = (const float*)d_in[15];
  const float* b2  = (const float*)d_in[16];
  float* out = (float*)d_out;

  char* ws = (char*)d_ws;
  __bf16* h    = (__bf16*)(ws);
  __bf16* qb   = (__bf16*)(ws + (size_t)8 * 1024 * 1024);
  __bf16* kb   = (__bf16*)(ws + (size_t)16 * 1024 * 1024);
  __bf16* vT   = (__bf16*)(ws + (size_t)24 * 1024 * 1024);
  float*  x2   = (float*)(ws + (size_t)32 * 1024 * 1024);
  __bf16* fb   = (__bf16*)(ws + (size_t)48 * 1024 * 1024);
  __bf16* wqkv = (__bf16*)(ws + (size_t)56 * 1024 * 1024);
  __bf16* wo   = wqkv + 3 * 512 * 512;
  __bf16* w1t  = wo + 512 * 512;
  __bf16* w2t  = w1t + 512 * 2048;
  __bf16* g1   = (__bf16*)(ws);

  k_transpose_all<<<12288, 256, 0, stream>>>(Wq, Wk, Wv, Wo, W1, W2, wqkv, wo, w1t, w2t);
  k_ln_rope<<<8192, 256, 0, stream>>>(x, lng, lnb, h);
  k_gemm_qkv<<<64 * 12, 256, 0, stream>>>(h, wqkv, bq, bk, bv, qb, kb, vT);
  k_attn<<<32 * 16, 512, 0, stream>>>(qb, kb, vT, h);  // o reuses h region
  k_gemm_oproj<<<64 * 4, 256, 0, stream>>>(h, wo, bo, x, x2);
  k_ln_ln<<<8192, 256, 0, stream>>>(x2, lng, lnb, ffg, ffb, fb);
  k_gemm_ffn1<<<64 * 16, 256, 0, stream>>>(fb, w1t, b1, g1);
  k_gemm_ffn2<<<64 * 4, 256, 0, stream>>>(g1, w2t, b2, x2, out);
}

// Round 8
// 277.122 us; speedup vs baseline: 1.0929x; 1.0929x over previous
//
#include <hip/hip_runtime.h>
#include <cmath>

typedef __bf16 bf16x8 __attribute__((ext_vector_type(8)));
typedef float  f32x4  __attribute__((ext_vector_type(4)));
typedef float  f32x16 __attribute__((ext_vector_type(16)));

#define MFMA(a, b, c)   __builtin_amdgcn_mfma_f32_16x16x32_bf16((a), (b), (c), 0, 0, 0)
#define MFMA32(a, b, c) __builtin_amdgcn_mfma_f32_32x32x16_bf16((a), (b), (c), 0, 0, 0)

static __device__ __forceinline__ __bf16 f2bf(float f) {
  union { float f; unsigned u; } v; v.f = f;
  unsigned r = v.u + 0x7fffu + ((v.u >> 16) & 1u);
  union { unsigned short u; __bf16 b; } o; o.u = (unsigned short)(r >> 16);
  return o.b;
}
// truncating convert (1 VALU op) — used only for the attention P tile
static __device__ __forceinline__ __bf16 f2bf_tr(float f) {
  union { float f; unsigned u; } v; v.f = f;
  union { unsigned short u; __bf16 b; } o; o.u = (unsigned short)(v.u >> 16);
  return o.b;
}

typedef const __attribute__((address_space(1))) void* gas_t;
typedef __attribute__((address_space(3))) void* las_t;
static __device__ __forceinline__ void load_lds16(const __bf16* g, __bf16* l) {
  __builtin_amdgcn_global_load_lds((gas_t)g, (las_t)l, 16, 0, 0);
}

// ---------------- all weight transposes fp32[K][N] -> bf16[N][K], one launch ----------------
__global__ __launch_bounds__(256) void k_transpose_all(
    const float* __restrict__ Wq, const float* __restrict__ Wk,
    const float* __restrict__ Wv, const float* __restrict__ Wo,
    const float* __restrict__ W1, const float* __restrict__ W2,
    __bf16* __restrict__ wqkv, __bf16* __restrict__ wo,
    __bf16* __restrict__ w1t, __bf16* __restrict__ w2t) {
  int idx = blockIdx.x * 256 + threadIdx.x;  // [0, 3145728)
  const float* src; __bf16* dst; int off, logK, N;
  if (idx < 1048576) {
    int which = idx >> 18; off = idx & 262143; logK = 9; N = 512;
    src = which == 0 ? Wq : which == 1 ? Wk : which == 2 ? Wv : Wo;
    dst = which < 3 ? wqkv + which * 262144 : wo;
  } else if (idx < 2097152) {
    off = idx - 1048576; logK = 9; N = 2048; src = W1; dst = w1t;
  } else {
    off = idx - 2097152; logK = 11; N = 512; src = W2; dst = w2t;
  }
  int n = off >> logK, k = off & ((1 << logK) - 1);
  dst[off] = f2bf(src[(size_t)k * N + n]);
}

// ---------------- LN + RoPE (full-dim rope, half=256) -> h bf16 ----------------
__global__ __launch_bounds__(256) void k_ln_rope(const float* __restrict__ x,
                                                 const float* __restrict__ g,
                                                 const float* __restrict__ b,
                                                 __bf16* __restrict__ h) {
  int n = blockIdx.x, tid = threadIdx.x;
  const float* row = x + (size_t)n * 512;
  float v1 = row[tid], v2 = row[tid + 256];
  float s = v1 + v2, ss = v1 * v1 + v2 * v2;
  #pragma unroll
  for (int off = 1; off < 64; off <<= 1) { s += __shfl_xor(s, off, 64); ss += __shfl_xor(ss, off, 64); }
  __shared__ float red[2][4];
  if ((tid & 63) == 0) { red[0][tid >> 6] = s; red[1][tid >> 6] = ss; }
  __syncthreads();
  s  = red[0][0] + red[0][1] + red[0][2] + red[0][3];
  ss = red[1][0] + red[1][1] + red[1][2] + red[1][3];
  float mu = s * (1.f / 512.f);
  float var = ss * (1.f / 512.f) - mu * mu;
  float rs = rsqrtf(var + 1e-5f);
  float y1 = (v1 - mu) * rs * g[tid] + b[tid];
  float y2 = (v2 - mu) * rs * g[tid + 256] + b[tid + 256];
  int t = n & 2047;
  float inv = __expf(-(float)tid * 0.03597789207803197f);
  float ang = (float)t * inv;
  float sn, c;
  __sincosf(ang, &sn, &c);
  h[(size_t)n * 512 + tid]       = f2bf(y1 * c - y2 * sn);
  h[(size_t)n * 512 + tid + 256] = f2bf(y1 * sn + y2 * c);
}

// ---------------- WIDE core: 128x128 block, 8 waves (32x64 each), BK=64, swizzled ----------------
// LDS: 128 rows x 8 chunks of 8 bf16; slot s of row r holds global k-chunk s^(r&7).
template <int K>
static __device__ __forceinline__ void gemm128(const __bf16* __restrict__ A,
                                               const __bf16* __restrict__ Bt,
                                               f32x4 (&acc)[2][4]) {
  __shared__ __bf16 lA[128 * 64];
  __shared__ __bf16 lB[128 * 64];
  int bm = blockIdx.x & 63, bn = blockIdx.x >> 6;
  int tid = threadIdx.x, w = tid >> 6, lane = tid & 63;
  int l16 = lane & 15, quad = lane >> 4;
  int wr = (w & 3) * 32, wc = (w >> 2) * 64;
  int srow = w * 8 + (lane >> 3);                 // staging row 0..63
  int sg = (lane & 7) ^ (srow & 7);               // global chunk for this slot
  const __bf16* ga = A  + (size_t)(bm * 128 + srow) * K + sg * 8;
  const __bf16* gb = Bt + (size_t)(bn * 128 + srow) * K + sg * 8;
  __bf16* saw = lA + w * 512;
  __bf16* sbw = lB + w * 512;
  #pragma unroll
  for (int i = 0; i < 2; ++i)
    #pragma unroll
    for (int j = 0; j < 4; ++j) acc[i][j] = {0.f, 0.f, 0.f, 0.f};
  const size_t rstep = (size_t)64 * K;
  for (int k0 = 0; k0 < K; k0 += 64) {
    load_lds16(ga + k0,         saw);
    load_lds16(ga + k0 + rstep, saw + 4096);
    load_lds16(gb + k0,         sbw);
    load_lds16(gb + k0 + rstep, sbw + 4096);
    __syncthreads();
    #pragma unroll
    for (int kk = 0; kk < 2; ++kk) {
      int gg = kk * 4 + quad;
      bf16x8 af[2], bfr[4];
      #pragma unroll
      for (int i = 0; i < 2; ++i) {
        int row = wr + i * 16 + l16;
        __builtin_memcpy(&af[i], &lA[row * 64 + ((gg ^ (row & 7)) * 8)], 16);
      }
      #pragma unroll
      for (int j = 0; j < 4; ++j) {
        int row = wc + j * 16 + l16;
        __builtin_memcpy(&bfr[j], &lB[row * 64 + ((gg ^ (row & 7)) * 8)], 16);
      }
      #pragma unroll
      for (int i = 0; i < 2; ++i)
        #pragma unroll
        for (int j = 0; j < 4; ++j) acc[i][j] = MFMA(af[i], bfr[j], acc[i][j]);
    }
    __syncthreads();
  }
}

#define G128_EPILOG_IDX                                 \
  int bm = blockIdx.x & 63, bn = blockIdx.x >> 6;       \
  int lane = threadIdx.x & 63, w = threadIdx.x >> 6;    \
  int l16 = lane & 15, quad = lane >> 4;                \
  int wr = (w & 3) * 32, wc = (w >> 2) * 64;

// ---------------- QKV GEMM: h[8192][512] @ Wqkv_t[1536][512] ----------------
__global__ __launch_bounds__(512) void k_gemm_qkv(const __bf16* __restrict__ A,
                                                  const __bf16* __restrict__ Bt,
                                                  const float* __restrict__ bq,
                                                  const float* __restrict__ bk,
                                                  const float* __restrict__ bv,
                                                  __bf16* __restrict__ qo,
                                                  __bf16* __restrict__ ko,
                                                  __bf16* __restrict__ vT) {
  f32x4 acc[2][4];
  gemm128<512>(A, Bt, acc);
  G128_EPILOG_IDX
  int proj = bn >> 2;
  const float* bias = proj == 0 ? bq : (proj == 1 ? bk : bv);
  float scale = proj == 0 ? 0.125f : 1.f;  // fold 1/sqrt(DH) into q
  if (proj < 2) {
    __bf16* dst = proj == 0 ? qo : ko;
    #pragma unroll
    for (int i = 0; i < 2; ++i)
      #pragma unroll
      for (int j = 0; j < 4; ++j)
        #pragma unroll
        for (int r = 0; r < 4; ++r) {
          int c = (bn * 128 + wc + j * 16 + l16) & 511;
          int m = bm * 128 + wr + i * 16 + quad * 4 + r;
          int bI = m >> 11, t = m & 2047;
          int head = c >> 6, dh = c & 63;
          dst[(((size_t)bI * 8 + head) * 2048 + t) * 64 + dh] = f2bf((acc[i][j][r] + bias[c]) * scale);
        }
  } else {
    #pragma unroll
    for (int i = 0; i < 2; ++i)
      #pragma unroll
      for (int j = 0; j < 4; ++j)
        #pragma unroll
        for (int r = 0; r < 4; ++r) {
          int c = (bn * 128 + wc + j * 16 + l16) & 511;
          int m = bm * 128 + wr + i * 16 + quad * 4 + r;
          int bI = m >> 11, t = m & 2047;
          int head = c >> 6, dh = c & 63;
          vT[(((size_t)bI * 8 + head) * 64 + dh) * 2048 + t] = f2bf(acc[i][j][r] + bias[c]);
        }
  }
}

// ---------------- NARROW core: 64x64 block, 8 waves, in-block split-K x2, BK=128 ----------------
// LDS: lA/lB 64 rows x 16 chunks of 8 bf16; slot s of row r holds global chunk s^(r&15).
// Waves: pos=w&3 -> 32x32 quadrant; half=w>>2 -> k-chunks [half*8, half*8+8) of each BK=128 tile.
// fp32 combine across halves through reused LDS at the end.
template <int K, typename EPI>
static __device__ __forceinline__ void gemm64sk(const __bf16* __restrict__ A,
                                                const __bf16* __restrict__ Bt,
                                                EPI epi) {
  __shared__ __align__(16) char smem[64 * 128 * 2 * 2];   // 32 KB, reused for combine
  __bf16* lA = (__bf16*)smem;
  __bf16* lB = lA + 64 * 128;
  int bm = blockIdx.x & 127, bn = blockIdx.x >> 7;
  int tid = threadIdx.x, w = tid >> 6, lane = tid & 63;
  int l16 = lane & 15, quad = lane >> 4;
  int pos = w & 3, half = w >> 2;
  int wr = (pos >> 1) * 32, wc = (pos & 1) * 32;
  // staging: thread t -> row t>>4 (0..31), slot t&15; second call rows +32
  int srow = tid >> 4;
  int sg = (tid & 15) ^ (srow & 15);
  const __bf16* ga = A  + (size_t)(bm * 64 + srow) * K + sg * 8;
  const __bf16* gb = Bt + (size_t)(bn * 64 + srow) * K + sg * 8;
  __bf16* sa = lA + w * 512;
  __bf16* sb = lB + w * 512;
  f32x4 acc[2][2];
  #pragma unroll
  for (int i = 0; i < 2; ++i)
    #pragma unroll
    for (int j = 0; j < 2; ++j) acc[i][j] = {0.f, 0.f, 0.f, 0.f};
  const size_t rstep = (size_t)32 * K;
  for (int k0 = 0; k0 < K; k0 += 128) {
    load_lds16(ga + k0,         sa);
    load_lds16(ga + k0 + rstep, sa + 4096);
    load_lds16(gb + k0,         sb);
    load_lds16(gb + k0 + rstep, sb + 4096);
    __syncthreads();
    #pragma unroll
    for (int kk = 0; kk < 2; ++kk) {
      int gg = half * 8 + kk * 4 + quad;
      bf16x8 af[2], bfr[2];
      #pragma unroll
      for (int i = 0; i < 2; ++i) {
        int row = wr + i * 16 + l16;
        __builtin_memcpy(&af[i], &lA[row * 128 + ((gg ^ (row & 15)) * 8)], 16);
      }
      #pragma unroll
      for (int j = 0; j < 2; ++j) {
        int row = wc + j * 16 + l16;
        __builtin_memcpy(&bfr[j], &lB[row * 128 + ((gg ^ (row & 15)) * 8)], 16);
      }
      #pragma unroll
      for (int i = 0; i < 2; ++i)
        #pragma unroll
        for (int j = 0; j < 2; ++j) acc[i][j] = MFMA(af[i], bfr[j], acc[i][j]);
    }
    __syncthreads();
  }
  // combine halves (LDS reuse is safe: loop ended with __syncthreads)
  float (*cbuf)[64][17] = (float(*)[64][17])smem;
  if (half) {
    #pragma unroll
    for (int i = 0; i < 2; ++i)
      #pragma unroll
      for (int j = 0; j < 2; ++j)
        #pragma unroll
        for (int r = 0; r < 4; ++r) cbuf[pos][lane][(i * 2 + j) * 4 + r] = acc[i][j][r];
  }
  __syncthreads();
  if (!half) {
    #pragma unroll
    for (int i = 0; i < 2; ++i)
      #pragma unroll
      for (int j = 0; j < 2; ++j)
        #pragma unroll
        for (int r = 0; r < 4; ++r) {
          float v = acc[i][j][r] + cbuf[pos][lane][(i * 2 + j) * 4 + r];
          int m = bm * 64 + wr + i * 16 + quad * 4 + r;
          int n = bn * 64 + wc + j * 16 + l16;
          epi(m, n, v);
        }
  }
}

// ---------------- O-proj + residual: x2 = x + o@Wo + bo (fp32 out) ----------------
__global__ __launch_bounds__(512) void k_gemm_oproj(const __bf16* __restrict__ A,
                                                    const __bf16* __restrict__ Bt,
                                                    const float* __restrict__ bo,
                                                    const float* __restrict__ xin,
                                                    float* __restrict__ x2) {
  gemm64sk<512>(A, Bt, [&](int m, int n, float v) {
    size_t idx = (size_t)m * 512 + n;
    x2[idx] = xin[idx] + v + bo[n];
  });
}

// ---------------- FFN2 + final residual -> out fp32 ----------------
__global__ __launch_bounds__(512) void k_gemm_ffn2(const __bf16* __restrict__ A,
                                                   const __bf16* __restrict__ Bt,
                                                   const float* __restrict__ b2,
                                                   const float* __restrict__ x2,
                                                   float* __restrict__ out) {
  gemm64sk<2048>(A, Bt, [&](int m, int n, float v) {
    size_t idx = (size_t)m * 512 + n;
    out[idx] = x2[idx] + v + b2[n];
  });
}

// ---------------- attention: 64-key iterations, all waves compute, swizzled LDS ----------------
__global__ __launch_bounds__(512) void k_attn(const __bf16* __restrict__ q,
                                              const __bf16* __restrict__ k,
                                              const __bf16* __restrict__ vT,
                                              __bf16* __restrict__ o) {
  __shared__ __align__(16) __bf16 Kt[64 * 64];
  __shared__ __align__(16) __bf16 Vt[64 * 64];
  __shared__ __align__(16) __bf16 P[8][32][40];   // per-wave 32x32 P, row stride 40
  __shared__ float cbuf[4][64][17];               // split-K combine
  int bh = blockIdx.x >> 4, qblk = blockIdx.x & 15;
  int tid = threadIdx.x, w = tid >> 6, lane = tid & 63;
  int l32 = lane & 31, h32 = lane >> 5;
  int qw = w & 3, half = w >> 2, hoff = half * 32;
  int qB = qblk * 128;
  int q0 = qB + qw * 32;
  const __bf16* qb = q + (size_t)bh * 2048 * 64;
  const __bf16* kb = k + (size_t)bh * 2048 * 64;
  const __bf16* vb = vT + (size_t)bh * 64 * 2048;
  bf16x8 aq[4];
  #pragma unroll
  for (int i = 0; i < 4; ++i)
    aq[i] = *(const bf16x8*)(qb + (size_t)(q0 + l32) * 64 + i * 16 + h32 * 8);
  f32x16 on0 = {0,0,0,0,0,0,0,0,0,0,0,0,0,0,0,0};
  f32x16 on1 = {0,0,0,0,0,0,0,0,0,0,0,0,0,0,0,0};
  float lsum[16];
  #pragma unroll
  for (int i = 0; i < 16; ++i) lsum[i] = 0.f;
  int srow = w * 8 + (lane >> 3);           // 0..63
  int sg = (lane & 7) ^ (srow & 7);
  const __bf16* gk = kb + (size_t)srow * 64 + sg * 8;
  const __bf16* gv = vb + (size_t)srow * 2048 + sg * 8;
  __bf16* skw = Kt + w * 512;
  __bf16* svw = Vt + w * 512;

  for (int it = 0; it < 32; ++it) {
    int kt64 = it * 64;
    if ((unsigned)(kt64 - qB) <= 64u) continue;  // fully banned for whole block
    load_lds16(gk + (size_t)kt64 * 64, skw);
    load_lds16(gv + kt64, svw);
    __syncthreads();
    int myk0 = kt64 + hoff;
    bool skip = (q0 + 31 - myk0 <= 128) && (myk0 + 31 - q0 <= 128);
    if (!skip) {
      bool need_mask = !((myk0 >= q0 + 160) || (myk0 <= q0 - 160));
      f32x16 sc = {0,0,0,0,0,0,0,0,0,0,0,0,0,0,0,0};
      int krow = hoff + l32;
      #pragma unroll
      for (int i = 0; i < 4; ++i) {
        int gg = i * 2 + h32;
        bf16x8 bk;
        __builtin_memcpy(&bk, &Kt[krow * 64 + ((gg ^ (l32 & 7)) * 8)], 16);
        sc = MFMA32(aq[i], bk, sc);
      }
      #pragma unroll
      for (int reg = 0; reg < 16; ++reg) {
        int row = (reg & 3) + 8 * (reg >> 2) + 4 * h32;
        float p = __expf(sc[reg]);   // scores pre-scaled by 1/8 via q; no max-shift needed
        if (need_mask) {
          int qi = q0 + row, kj = myk0 + l32;
          if ((unsigned)(qi - kj + 128) <= 256u) p = 0.f;
        }
        P[w][row][l32] = f2bf_tr(p);
        lsum[reg] += p;
      }
      bf16x8 ap0, ap1;
      __builtin_memcpy(&ap0, &P[w][l32][h32 * 8], 16);
      __builtin_memcpy(&ap1, &P[w][l32][16 + h32 * 8], 16);
      #pragma unroll
      for (int kk = 0; kk < 2; ++kk) {
        bf16x8 ap = kk ? ap1 : ap0;
        int gg = half * 4 + kk * 2 + h32;
        bf16x8 bv0, bv1;
        __builtin_memcpy(&bv0, &Vt[l32 * 64 + ((gg ^ (l32 & 7)) * 8)], 16);
        __builtin_memcpy(&bv1, &Vt[(32 + l32) * 64 + ((gg ^ (l32 & 7)) * 8)], 16);
        on0 = MFMA32(ap, bv0, on0);
        on1 = MFMA32(ap, bv1, on1);
      }
    }
    __syncthreads();
  }
  // -------- split-K combine (3 phases through cbuf) --------
  if (half) {
    for (int i = 0; i < 16; ++i) cbuf[qw][lane][i] = on0[i];
  }
  __syncthreads();
  if (!half) {
    for (int i = 0; i < 16; ++i) on0[i] += cbuf[qw][lane][i];
  }
  __syncthreads();
  if (half) {
    for (int i = 0; i < 16; ++i) cbuf[qw][lane][i] = on1[i];
  }
  __syncthreads();
  if (!half) {
    for (int i = 0; i < 16; ++i) on1[i] += cbuf[qw][lane][i];
  }
  __syncthreads();
  if (half) {
    for (int i = 0; i < 16; ++i) cbuf[qw][lane][i] = lsum[i];
  }
  __syncthreads();
  if (!half) {
    #pragma unroll
    for (int i = 0; i < 16; ++i) {
      float s = lsum[i] + cbuf[qw][lane][i];
      #pragma unroll
      for (int off = 1; off < 32; off <<= 1) s += __shfl_xor(s, off, 64);
      lsum[i] = 1.f / s;
    }
    int bI = bh >> 3, head = bh & 7;
    #pragma unroll
    for (int reg = 0; reg < 16; ++reg) {
      int row = (reg & 3) + 8 * (reg >> 2) + 4 * h32;
      size_t base = ((size_t)(bI * 2048 + q0 + row)) * 512 + head * 64;
      o[base + l32]      = f2bf(on0[reg] * lsum[reg]);
      o[base + 32 + l32] = f2bf(on1[reg] * lsum[reg]);
    }
  }
}

// ---------------- double layernorm -> f bf16 ----------------
__global__ __launch_bounds__(256) void k_ln_ln(const float* __restrict__ x2,
                                               const float* __restrict__ g1v,
                                               const float* __restrict__ b1v,
                                               const float* __restrict__ g2v,
                                               const float* __restrict__ b2v,
                                               __bf16* __restrict__ fout) {
  int n = blockIdx.x, tid = threadIdx.x;
  const float* row = x2 + (size_t)n * 512;
  float v1 = row[tid], v2 = row[tid + 256];
  __shared__ float red[2][4];
  float s = v1 + v2, ss = v1 * v1 + v2 * v2;
  #pragma unroll
  for (int off = 1; off < 64; off <<= 1) { s += __shfl_xor(s, off, 64); ss += __shfl_xor(ss, off, 64); }
  if ((tid & 63) == 0) { red[0][tid >> 6] = s; red[1][tid >> 6] = ss; }
  __syncthreads();
  s  = red[0][0] + red[0][1] + red[0][2] + red[0][3];
  ss = red[1][0] + red[1][1] + red[1][2] + red[1][3];
  float mu = s * (1.f / 512.f), var = ss * (1.f / 512.f) - mu * mu;
  float rs = rsqrtf(var + 1e-5f);
  float y1 = (v1 - mu) * rs * g1v[tid] + b1v[tid];
  float y2 = (v2 - mu) * rs * g1v[tid + 256] + b1v[tid + 256];
  __syncthreads();
  s = y1 + y2; ss = y1 * y1 + y2 * y2;
  #pragma unroll
  for (int off = 1; off < 64; off <<= 1) { s += __shfl_xor(s, off, 64); ss += __shfl_xor(ss, off, 64); }
  if ((tid & 63) == 0) { red[0][tid >> 6] = s; red[1][tid >> 6] = ss; }
  __syncthreads();
  s  = red[0][0] + red[0][1] + red[0][2] + red[0][3];
  ss = red[1][0] + red[1][1] + red[1][2] + red[1][3];
  float mu2 = s * (1.f / 512.f), var2 = ss * (1.f / 512.f) - mu2 * mu2;
  float rs2 = rsqrtf(var2 + 1e-5f);
  fout[(size_t)n * 512 + tid]       = f2bf((y1 - mu2) * rs2 * g2v[tid] + b2v[tid]);
  fout[(size_t)n * 512 + tid + 256] = f2bf((y2 - mu2) * rs2 * g2v[tid + 256] + b2v[tid + 256]);
}

// ---------------- FFN1 + exact GELU -> g1 bf16 ----------------
__global__ __launch_bounds__(512) void k_gemm_ffn1(const __bf16* __restrict__ A,
                                                   const __bf16* __restrict__ Bt,
                                                   const float* __restrict__ b1,
                                                   __bf16* __restrict__ g1) {
  f32x4 acc[2][4];
  gemm128<512>(A, Bt, acc);
  G128_EPILOG_IDX
  #pragma unroll
  for (int i = 0; i < 2; ++i)
    #pragma unroll
    for (int j = 0; j < 4; ++j)
      #pragma unroll
      for (int r = 0; r < 4; ++r) {
        int n = bn * 128 + wc + j * 16 + l16;
        int m = bm * 128 + wr + i * 16 + quad * 4 + r;
        float t = acc[i][j][r] + b1[n];
        float ge = 0.5f * t * (1.f + erff(t * 0.7071067811865475f));
        g1[(size_t)m * 2048 + n] = f2bf(ge);
      }
}

extern "C" void kernel_launch(void* const* d_in, const int* in_sizes, int n_in,
                              void* d_out, int out_size, void* d_ws, size_t ws_size,
                              hipStream_t stream) {
  (void)in_sizes; (void)n_in; (void)out_size; (void)ws_size;
  const float* x   = (const float*)d_in[0];
  const float* Wq  = (const float*)d_in[1];
  const float* bq  = (const float*)d_in[2];
  const float* Wk  = (const float*)d_in[3];
  const float* bk  = (const float*)d_in[4];
  const float* Wv  = (const float*)d_in[5];
  const float* bv  = (const float*)d_in[6];
  const float* Wo  = (const float*)d_in[7];
  const float* bo  = (const float*)d_in[8];
  const float* lng = (const float*)d_in[9];
  const float* lnb = (const float*)d_in[10];
  const float* ffg = (const float*)d_in[11];
  const float* ffb = (const float*)d_in[12];
  const float* W1  = (const float*)d_in[13];
  const float* b1  = (const float*)d_in[14];
  const float* W2  = (const float*)d_in[15];
  const float* b2  = (const float*)d_in[16];
  float* out = (float*)d_out;

  char* ws = (char*)d_ws;
  __bf16* h    = (__bf16*)(ws);
  __bf16* qb   = (__bf16*)(ws + (size_t)8 * 1024 * 1024);
  __bf16* kb   = (__bf16*)(ws + (size_t)16 * 1024 * 1024);
  __bf16* vT   = (__bf16*)(ws + (size_t)24 * 1024 * 1024);
  float*  x2   = (float*)(ws + (size_t)32 * 1024 * 1024);
  __bf16* fb   = (__bf16*)(ws + (size_t)48 * 1024 * 1024);
  __bf16* wqkv = (__bf16*)(ws + (size_t)56 * 1024 * 1024);
  __bf16* wo   = wqkv + 3 * 512 * 512;
  __bf16* w1t  = wo + 512 * 512;
  __bf16* w2t  = w1t + 512 * 2048;
  __bf16* g1   = (__bf16*)(ws);

  k_transpose_all<<<12288, 256, 0, stream>>>(Wq, Wk, Wv, Wo, W1, W2, wqkv, wo, w1t, w2t);
  k_ln_rope<<<8192, 256, 0, stream>>>(x, lng, lnb, h);
  k_gemm_qkv<<<64 * 12, 512, 0, stream>>>(h, wqkv, bq, bk, bv, qb, kb, vT);
  k_attn<<<32 * 16, 512, 0, stream>>>(qb, kb, vT, h);  // o reuses h region
  k_gemm_oproj<<<128 * 8, 512, 0, stream>>>(h, wo, bo, x, x2);
  k_ln_ln<<<8192, 256, 0, stream>>>(x2, lng, lnb, ffg, ffb, fb);
  k_gemm_ffn1<<<64 * 16, 512, 0, stream>>>(fb, w1t, b1, g1);
  k_gemm_ffn2<<<128 * 8, 512, 0, stream>>>(g1, w2t, b2, x2, out);
}

// Round 9
// 276.965 us; speedup vs baseline: 1.0935x; 1.0006x over previous
//
#include <hip/hip_runtime.h>
#include <cmath>

typedef __bf16 bf16x8 __attribute__((ext_vector_type(8)));
typedef float  f32x4  __attribute__((ext_vector_type(4)));
typedef float  f32x16 __attribute__((ext_vector_type(16)));
typedef int    i32x4  __attribute__((ext_vector_type(4)));

#define MFMA(a, b, c)   __builtin_amdgcn_mfma_f32_16x16x32_bf16((a), (b), (c), 0, 0, 0)
#define MFMA32(a, b, c) __builtin_amdgcn_mfma_f32_32x32x16_bf16((a), (b), (c), 0, 0, 0)

static __device__ __forceinline__ unsigned fbits(float f) {
  union { float f; unsigned u; } v; v.f = f; return v.u;
}
static __device__ __forceinline__ __bf16 f2bf(float f) {
  unsigned u = fbits(f);
  unsigned r = u + 0x7fffu + ((u >> 16) & 1u);
  union { unsigned short u; __bf16 b; } o; o.u = (unsigned short)(r >> 16);
  return o.b;
}
// pack two floats -> two rounded bf16 in one dword (low = a, high = b)
static __device__ __forceinline__ unsigned pack2rn(float a, float b) {
  unsigned ua = fbits(a); ua = ua + 0x7fffu + ((ua >> 16) & 1u);
  unsigned ub = fbits(b); ub = ub + 0x7fffu + ((ub >> 16) & 1u);
  return __builtin_amdgcn_perm(ub, ua, 0x07060302);
}

typedef const __attribute__((address_space(1))) void* gas_t;
typedef __attribute__((address_space(3))) void* las_t;
static __device__ __forceinline__ void load_lds16(const __bf16* g, __bf16* l) {
  __builtin_amdgcn_global_load_lds((gas_t)g, (las_t)l, 16, 0, 0);
}

// ---------------- fused preprocessing: weight transposes + LN+RoPE ----------------
__global__ __launch_bounds__(256) void k_pre(
    const float* __restrict__ Wq, const float* __restrict__ Wk,
    const float* __restrict__ Wv, const float* __restrict__ Wo,
    const float* __restrict__ W1, const float* __restrict__ W2,
    __bf16* __restrict__ wqkv, __bf16* __restrict__ wo,
    __bf16* __restrict__ w1t, __bf16* __restrict__ w2t,
    const float* __restrict__ x, const float* __restrict__ g,
    const float* __restrict__ b, __bf16* __restrict__ h) {
  if (blockIdx.x < 12288) {
    int idx = blockIdx.x * 256 + threadIdx.x;  // [0, 3145728)
    const float* src; __bf16* dst; int off, logK, N;
    if (idx < 1048576) {
      int which = idx >> 18; off = idx & 262143; logK = 9; N = 512;
      src = which == 0 ? Wq : which == 1 ? Wk : which == 2 ? Wv : Wo;
      dst = which < 3 ? wqkv + which * 262144 : wo;
    } else if (idx < 2097152) {
      off = idx - 1048576; logK = 9; N = 2048; src = W1; dst = w1t;
    } else {
      off = idx - 2097152; logK = 11; N = 512; src = W2; dst = w2t;
    }
    int n = off >> logK, k = off & ((1 << logK) - 1);
    dst[off] = f2bf(src[(size_t)k * N + n]);
    return;
  }
  int n = blockIdx.x - 12288, tid = threadIdx.x;
  const float* row = x + (size_t)n * 512;
  float v1 = row[tid], v2 = row[tid + 256];
  float s = v1 + v2, ss = v1 * v1 + v2 * v2;
  #pragma unroll
  for (int off = 1; off < 64; off <<= 1) { s += __shfl_xor(s, off, 64); ss += __shfl_xor(ss, off, 64); }
  __shared__ float red[2][4];
  if ((tid & 63) == 0) { red[0][tid >> 6] = s; red[1][tid >> 6] = ss; }
  __syncthreads();
  s  = red[0][0] + red[0][1] + red[0][2] + red[0][3];
  ss = red[1][0] + red[1][1] + red[1][2] + red[1][3];
  float mu = s * (1.f / 512.f);
  float var = ss * (1.f / 512.f) - mu * mu;
  float rs = rsqrtf(var + 1e-5f);
  float y1 = (v1 - mu) * rs * g[tid] + b[tid];
  float y2 = (v2 - mu) * rs * g[tid + 256] + b[tid + 256];
  int t = n & 2047;
  float inv = __expf(-(float)tid * 0.03597789207803197f);
  float ang = (float)t * inv;
  float sn, c;
  __sincosf(ang, &sn, &c);
  h[(size_t)n * 512 + tid]       = f2bf(y1 * c - y2 * sn);
  h[(size_t)n * 512 + tid + 256] = f2bf(y1 * sn + y2 * c);
}

// ---------------- WIDE core: 128x128 block, 8 waves (32x64 each), BK=64, swizzled ----------------
template <int K>
static __device__ __forceinline__ void gemm128(const __bf16* __restrict__ A,
                                               const __bf16* __restrict__ Bt,
                                               f32x4 (&acc)[2][4]) {
  __shared__ __bf16 lA[128 * 64];
  __shared__ __bf16 lB[128 * 64];
  int bm = blockIdx.x & 63, bn = blockIdx.x >> 6;
  int tid = threadIdx.x, w = tid >> 6, lane = tid & 63;
  int l16 = lane & 15, quad = lane >> 4;
  int wr = (w & 3) * 32, wc = (w >> 2) * 64;
  int srow = w * 8 + (lane >> 3);
  int sg = (lane & 7) ^ (srow & 7);
  const __bf16* ga = A  + (size_t)(bm * 128 + srow) * K + sg * 8;
  const __bf16* gb = Bt + (size_t)(bn * 128 + srow) * K + sg * 8;
  __bf16* saw = lA + w * 512;
  __bf16* sbw = lB + w * 512;
  #pragma unroll
  for (int i = 0; i < 2; ++i)
    #pragma unroll
    for (int j = 0; j < 4; ++j) acc[i][j] = {0.f, 0.f, 0.f, 0.f};
  const size_t rstep = (size_t)64 * K;
  for (int k0 = 0; k0 < K; k0 += 64) {
    load_lds16(ga + k0,         saw);
    load_lds16(ga + k0 + rstep, saw + 4096);
    load_lds16(gb + k0,         sbw);
    load_lds16(gb + k0 + rstep, sbw + 4096);
    __syncthreads();
    #pragma unroll
    for (int kk = 0; kk < 2; ++kk) {
      int gg = kk * 4 + quad;
      bf16x8 af[2], bfr[4];
      #pragma unroll
      for (int i = 0; i < 2; ++i) {
        int row = wr + i * 16 + l16;
        __builtin_memcpy(&af[i], &lA[row * 64 + ((gg ^ (row & 7)) * 8)], 16);
      }
      #pragma unroll
      for (int j = 0; j < 4; ++j) {
        int row = wc + j * 16 + l16;
        __builtin_memcpy(&bfr[j], &lB[row * 64 + ((gg ^ (row & 7)) * 8)], 16);
      }
      #pragma unroll
      for (int i = 0; i < 2; ++i)
        #pragma unroll
        for (int j = 0; j < 4; ++j) acc[i][j] = MFMA(af[i], bfr[j], acc[i][j]);
    }
    __syncthreads();
  }
}

#define G128_EPILOG_IDX                                 \
  int bm = blockIdx.x & 63, bn = blockIdx.x >> 6;       \
  int lane = threadIdx.x & 63, w = threadIdx.x >> 6;    \
  int l16 = lane & 15, quad = lane >> 4;                \
  int wr = (w & 3) * 32, wc = (w >> 2) * 64;

// ---------------- QKV GEMM: h[8192][512] @ Wqkv_t[1536][512] ----------------
__global__ __launch_bounds__(512) void k_gemm_qkv(const __bf16* __restrict__ A,
                                                  const __bf16* __restrict__ Bt,
                                                  const float* __restrict__ bq,
                                                  const float* __restrict__ bk,
                                                  const float* __restrict__ bv,
                                                  __bf16* __restrict__ qo,
                                                  __bf16* __restrict__ ko,
                                                  __bf16* __restrict__ vT) {
  f32x4 acc[2][4];
  gemm128<512>(A, Bt, acc);
  G128_EPILOG_IDX
  int proj = bn >> 2;
  const float* bias = proj == 0 ? bq : (proj == 1 ? bk : bv);
  float scale = proj == 0 ? 0.125f : 1.f;  // fold 1/sqrt(DH) into q
  if (proj < 2) {
    __bf16* dst = proj == 0 ? qo : ko;
    #pragma unroll
    for (int i = 0; i < 2; ++i)
      #pragma unroll
      for (int j = 0; j < 4; ++j)
        #pragma unroll
        for (int r = 0; r < 4; ++r) {
          int c = (bn * 128 + wc + j * 16 + l16) & 511;
          int m = bm * 128 + wr + i * 16 + quad * 4 + r;
          int bI = m >> 11, t = m & 2047;
          int head = c >> 6, dh = c & 63;
          dst[(((size_t)bI * 8 + head) * 2048 + t) * 64 + dh] = f2bf((acc[i][j][r] + bias[c]) * scale);
        }
  } else {
    #pragma unroll
    for (int i = 0; i < 2; ++i)
      #pragma unroll
      for (int j = 0; j < 4; ++j)
        #pragma unroll
        for (int r = 0; r < 4; ++r) {
          int c = (bn * 128 + wc + j * 16 + l16) & 511;
          int m = bm * 128 + wr + i * 16 + quad * 4 + r;
          int bI = m >> 11, t = m & 2047;
          int head = c >> 6, dh = c & 63;
          vT[(((size_t)bI * 8 + head) * 64 + dh) * 2048 + t] = f2bf(acc[i][j][r] + bias[c]);
        }
  }
}

// ---------------- NARROW core: 64x64 block, 8 waves, in-block split-K x2, BK=128 ----------------
template <int K, typename EPI>
static __device__ __forceinline__ void gemm64sk(const __bf16* __restrict__ A,
                                                const __bf16* __restrict__ Bt,
                                                EPI epi) {
  __shared__ __align__(16) char smem[64 * 128 * 2 * 2];   // 32 KB, reused for combine
  __bf16* lA = (__bf16*)smem;
  __bf16* lB = lA + 64 * 128;
  int bm = blockIdx.x & 127, bn = blockIdx.x >> 7;
  int tid = threadIdx.x, w = tid >> 6, lane = tid & 63;
  int l16 = lane & 15, quad = lane >> 4;
  int pos = w & 3, half = w >> 2;
  int wr = (pos >> 1) * 32, wc = (pos & 1) * 32;
  int srow = tid >> 4;
  int sg = (tid & 15) ^ (srow & 15);
  const __bf16* ga = A  + (size_t)(bm * 64 + srow) * K + sg * 8;
  const __bf16* gb = Bt + (size_t)(bn * 64 + srow) * K + sg * 8;
  __bf16* sa = lA + w * 512;
  __bf16* sb = lB + w * 512;
  f32x4 acc[2][2];
  #pragma unroll
  for (int i = 0; i < 2; ++i)
    #pragma unroll
    for (int j = 0; j < 2; ++j) acc[i][j] = {0.f, 0.f, 0.f, 0.f};
  const size_t rstep = (size_t)32 * K;
  for (int k0 = 0; k0 < K; k0 += 128) {
    load_lds16(ga + k0,         sa);
    load_lds16(ga + k0 + rstep, sa + 4096);
    load_lds16(gb + k0,         sb);
    load_lds16(gb + k0 + rstep, sb + 4096);
    __syncthreads();
    #pragma unroll
    for (int kk = 0; kk < 2; ++kk) {
      int gg = half * 8 + kk * 4 + quad;
      bf16x8 af[2], bfr[2];
      #pragma unroll
      for (int i = 0; i < 2; ++i) {
        int row = wr + i * 16 + l16;
        __builtin_memcpy(&af[i], &lA[row * 128 + ((gg ^ (row & 15)) * 8)], 16);
      }
      #pragma unroll
      for (int j = 0; j < 2; ++j) {
        int row = wc + j * 16 + l16;
        __builtin_memcpy(&bfr[j], &lB[row * 128 + ((gg ^ (row & 15)) * 8)], 16);
      }
      #pragma unroll
      for (int i = 0; i < 2; ++i)
        #pragma unroll
        for (int j = 0; j < 2; ++j) acc[i][j] = MFMA(af[i], bfr[j], acc[i][j]);
    }
    __syncthreads();
  }
  float (*cbuf)[64][17] = (float(*)[64][17])smem;
  if (half) {
    #pragma unroll
    for (int i = 0; i < 2; ++i)
      #pragma unroll
      for (int j = 0; j < 2; ++j)
        #pragma unroll
        for (int r = 0; r < 4; ++r) cbuf[pos][lane][(i * 2 + j) * 4 + r] = acc[i][j][r];
  }
  __syncthreads();
  if (!half) {
    #pragma unroll
    for (int i = 0; i < 2; ++i)
      #pragma unroll
      for (int j = 0; j < 2; ++j)
        #pragma unroll
        for (int r = 0; r < 4; ++r) {
          float v = acc[i][j][r] + cbuf[pos][lane][(i * 2 + j) * 4 + r];
          int m = bm * 64 + wr + i * 16 + quad * 4 + r;
          int n = bn * 64 + wc + j * 16 + l16;
          epi(m, n, v);
        }
  }
}

// ---------------- O-proj + residual: x2 = x + o@Wo + bo (fp32 out) ----------------
__global__ __launch_bounds__(512) void k_gemm_oproj(const __bf16* __restrict__ A,
                                                    const __bf16* __restrict__ Bt,
                                                    const float* __restrict__ bo,
                                                    const float* __restrict__ xin,
                                                    float* __restrict__ x2) {
  gemm64sk<512>(A, Bt, [&](int m, int n, float v) {
    size_t idx = (size_t)m * 512 + n;
    x2[idx] = xin[idx] + v + bo[n];
  });
}

// ---------------- FFN2 + final residual -> out fp32 ----------------
__global__ __launch_bounds__(512) void k_gemm_ffn2(const __bf16* __restrict__ A,
                                                   const __bf16* __restrict__ Bt,
                                                   const float* __restrict__ b2,
                                                   const float* __restrict__ x2,
                                                   float* __restrict__ out) {
  gemm64sk<2048>(A, Bt, [&](int m, int n, float v) {
    size_t idx = (size_t)m * 512 + n;
    out[idx] = x2[idx] + v + b2[n];
  });
}

// ---------------- attention: S^T form — P stays in registers (no LDS round-trip) ----------------
// Block = 128 q (4 q-waves x 32) x 2 key-halves. QK^T computed transposed (A=K, B=Q) so
// the C-layout of S^T (col=q=lane, row=k=reg) matches the PV B-operand (P^T) after a
// half-wave shfl_xor(32) exchange of packed bf16 pairs. O accumulates transposed
// (col=q, row=dh) -> packed b64 output stores. lsum is one scalar per lane.
__global__ __launch_bounds__(512) void k_attn(const __bf16* __restrict__ q,
                                              const __bf16* __restrict__ k,
                                              const __bf16* __restrict__ vT,
                                              __bf16* __restrict__ o) {
  __shared__ __align__(16) __bf16 Kt[64 * 64];
  __shared__ __align__(16) __bf16 Vt[64 * 64];
  __shared__ float cbuf[4][64][17];
  int bh = blockIdx.x >> 4, qblk = blockIdx.x & 15;
  int tid = threadIdx.x, w = tid >> 6, lane = tid & 63;
  int l32 = lane & 31, h32 = lane >> 5;
  int qw = w & 3, half = w >> 2, hoff = half * 32;
  int qB = qblk * 128;
  int q0 = qB + qw * 32;
  int qglob = q0 + l32;
  const __bf16* qb = q + (size_t)bh * 2048 * 64;
  const __bf16* kb = k + (size_t)bh * 2048 * 64;
  const __bf16* vb = vT + (size_t)bh * 64 * 2048;
  // Q fragments (B operand): lane n=l32 -> row qglob, dh = i*16 + h32*8 + j
  bf16x8 aq[4];
  #pragma unroll
  for (int i = 0; i < 4; ++i)
    aq[i] = *(const bf16x8*)(qb + (size_t)qglob * 64 + i * 16 + h32 * 8);
  f32x16 on0 = {0,0,0,0,0,0,0,0,0,0,0,0,0,0,0,0};
  f32x16 on1 = {0,0,0,0,0,0,0,0,0,0,0,0,0,0,0,0};
  float lsum = 0.f;
  int srow = w * 8 + (lane >> 3);
  int sg = (lane & 7) ^ (srow & 7);
  const __bf16* gk = kb + (size_t)srow * 64 + sg * 8;
  const __bf16* gv = vb + (size_t)srow * 2048 + sg * 8;
  __bf16* skw = Kt + w * 512;
  __bf16* svw = Vt + w * 512;

  for (int it = 0; it < 32; ++it) {
    int kt64 = it * 64;
    if ((unsigned)(kt64 - qB) <= 64u) continue;  // fully banned for whole block
    load_lds16(gk + (size_t)kt64 * 64, skw);
    load_lds16(gv + kt64, svw);
    __syncthreads();
    int myk0 = kt64 + hoff;
    bool skip = (q0 + 31 - myk0 <= 128) && (myk0 + 31 - q0 <= 128);
    if (!skip) {
      bool need_mask = !((myk0 >= q0 + 160) || (myk0 <= q0 - 160));
      f32x16 sc = {0,0,0,0,0,0,0,0,0,0,0,0,0,0,0,0};
      int krow = hoff + l32;
      #pragma unroll
      for (int i = 0; i < 4; ++i) {
        int gg = i * 2 + h32;
        bf16x8 bk;
        __builtin_memcpy(&bk, &Kt[krow * 64 + ((gg ^ (krow & 7)) * 8)], 16);
        sc = MFMA32(bk, aq[i], sc);   // S^T: A=K, B=Q
      }
      // exp + mask + pack pairs (truncating bf16 via v_perm)
      unsigned pk[8];
      #pragma unroll
      for (int g2 = 0; g2 < 8; ++g2) {
        int r0 = 2 * g2;
        float p0 = __expf(sc[r0]);
        float p1 = __expf(sc[r0 + 1]);
        if (need_mask) {
          int k0l = (r0 & 3) + 8 * (r0 >> 2) + 4 * h32;
          if ((unsigned)(qglob - (myk0 + k0l) + 128) <= 256u) p0 = 0.f;
          if ((unsigned)(qglob - (myk0 + k0l + 1) + 128) <= 256u) p1 = 0.f;
        }
        lsum += p0 + p1;
        pk[g2] = __builtin_amdgcn_perm(fbits(p1), fbits(p0), 0x07060302);
      }
      // half-wave exchange -> P^T B-fragments
      unsigned ex[8];
      #pragma unroll
      for (int g2 = 0; g2 < 8; ++g2) ex[g2] = (unsigned)__shfl_xor((int)pk[g2], 32);
      #pragma unroll
      for (int kk = 0; kk < 2; ++kk) {
        int o4 = kk * 4;
        i32x4 fi;
        fi.x = (int)(h32 ? ex[o4 + 2] : pk[o4 + 0]);
        fi.y = (int)(h32 ? ex[o4 + 3] : pk[o4 + 1]);
        fi.z = (int)(h32 ? pk[o4 + 2] : ex[o4 + 0]);
        fi.w = (int)(h32 ? pk[o4 + 3] : ex[o4 + 1]);
        bf16x8 pf;
        __builtin_memcpy(&pf, &fi, 16);
        int gg = half * 4 + kk * 2 + h32;
        bf16x8 bv0, bv1;
        __builtin_memcpy(&bv0, &Vt[l32 * 64 + ((gg ^ (l32 & 7)) * 8)], 16);
        __builtin_memcpy(&bv1, &Vt[(32 + l32) * 64 + ((gg ^ (l32 & 7)) * 8)], 16);
        on0 = MFMA32(bv0, pf, on0);   // O^T: A=V^T, B=P^T
        on1 = MFMA32(bv1, pf, on1);
      }
    }
    __syncthreads();
  }
  // -------- split-K combine (3 phases through cbuf) --------
  if (half) {
    for (int i = 0; i < 16; ++i) cbuf[qw][lane][i] = on0[i];
  }
  __syncthreads();
  if (!half) {
    for (int i = 0; i < 16; ++i) on0[i] += cbuf[qw][lane][i];
  }
  __syncthreads();
  if (half) {
    for (int i = 0; i < 16; ++i) cbuf[qw][lane][i] = on1[i];
  }
  __syncthreads();
  if (!half) {
    for (int i = 0; i < 16; ++i) on1[i] += cbuf[qw][lane][i];
  }
  __syncthreads();
  if (half) {
    cbuf[qw][lane][0] = lsum;
  }
  __syncthreads();
  if (!half) {
    float s = lsum + cbuf[qw][lane][0];
    s += __shfl_xor(s, 32);
    float rl = 1.f / s;
    int bI = bh >> 3, head = bh & 7;
    // lane holds q = qglob; on0/on1 regs -> dh = (reg&3) + 8*(reg>>2) + 4*h32 (+32 for on1)
    __bf16* obase = o + ((size_t)(bI * 2048 + qglob)) * 512 + head * 64 + 4 * h32;
    #pragma unroll
    for (int g2 = 0; g2 < 4; ++g2) {
      int r0 = 4 * g2;
      int2 v0, v1;
      v0.x = (int)pack2rn(on0[r0] * rl, on0[r0 + 1] * rl);
      v0.y = (int)pack2rn(on0[r0 + 2] * rl, on0[r0 + 3] * rl);
      v1.x = (int)pack2rn(on1[r0] * rl, on1[r0 + 1] * rl);
      v1.y = (int)pack2rn(on1[r0 + 2] * rl, on1[r0 + 3] * rl);
      *(int2*)(obase + 8 * g2) = v0;
      *(int2*)(obase + 32 + 8 * g2) = v1;
    }
  }
}

// ---------------- double layernorm -> f bf16 ----------------
__global__ __launch_bounds__(256) void k_ln_ln(const float* __restrict__ x2,
                                               const float* __restrict__ g1v,
                                               const float* __restrict__ b1v,
                                               const float* __restrict__ g2v,
                                               const float* __restrict__ b2v,
                                               __bf16* __restrict__ fout) {
  int n = blockIdx.x, tid = threadIdx.x;
  const float* row = x2 + (size_t)n * 512;
  float v1 = row[tid], v2 = row[tid + 256];
  __shared__ float red[2][4];
  float s = v1 + v2, ss = v1 * v1 + v2 * v2;
  #pragma unroll
  for (int off = 1; off < 64; off <<= 1) { s += __shfl_xor(s, off, 64); ss += __shfl_xor(ss, off, 64); }
  if ((tid & 63) == 0) { red[0][tid >> 6] = s; red[1][tid >> 6] = ss; }
  __syncthreads();
  s  = red[0][0] + red[0][1] + red[0][2] + red[0][3];
  ss = red[1][0] + red[1][1] + red[1][2] + red[1][3];
  float mu = s * (1.f / 512.f), var = ss * (1.f / 512.f) - mu * mu;
  float rs = rsqrtf(var + 1e-5f);
  float y1 = (v1 - mu) * rs * g1v[tid] + b1v[tid];
  float y2 = (v2 - mu) * rs * g1v[tid + 256] + b1v[tid + 256];
  __syncthreads();
  s = y1 + y2; ss = y1 * y1 + y2 * y2;
  #pragma unroll
  for (int off = 1; off < 64; off <<= 1) { s += __shfl_xor(s, off, 64); ss += __shfl_xor(ss, off, 64); }
  if ((tid & 63) == 0) { red[0][tid >> 6] = s; red[1][tid >> 6] = ss; }
  __syncthreads();
  s  = red[0][0] + red[0][1] + red[0][2] + red[0][3];
  ss = red[1][0] + red[1][1] + red[1][2] + red[1][3];
  float mu2 = s * (1.f / 512.f), var2 = ss * (1.f / 512.f) - mu2 * mu2;
  float rs2 = rsqrtf(var2 + 1e-5f);
  fout[(size_t)n * 512 + tid]       = f2bf((y1 - mu2) * rs2 * g2v[tid] + b2v[tid]);
  fout[(size_t)n * 512 + tid + 256] = f2bf((y2 - mu2) * rs2 * g2v[tid + 256] + b2v[tid + 256]);
}

// ---------------- FFN1 + exact GELU -> g1 bf16 ----------------
__global__ __launch_bounds__(512) void k_gemm_ffn1(const __bf16* __restrict__ A,
                                                   const __bf16* __restrict__ Bt,
                                                   const float* __restrict__ b1,
                                                   __bf16* __restrict__ g1) {
  f32x4 acc[2][4];
  gemm128<512>(A, Bt, acc);
  G128_EPILOG_IDX
  #pragma unroll
  for (int i = 0; i < 2; ++i)
    #pragma unroll
    for (int j = 0; j < 4; ++j)
      #pragma unroll
      for (int r = 0; r < 4; ++r) {
        int n = bn * 128 + wc + j * 16 + l16;
        int m = bm * 128 + wr + i * 16 + quad * 4 + r;
        float t = acc[i][j][r] + b1[n];
        float ge = 0.5f * t * (1.f + erff(t * 0.7071067811865475f));
        g1[(size_t)m * 2048 + n] = f2bf(ge);
      }
}

extern "C" void kernel_launch(void* const* d_in, const int* in_sizes, int n_in,
                              void* d_out, int out_size, void* d_ws, size_t ws_size,
                              hipStream_t stream) {
  (void)in_sizes; (void)n_in; (void)out_size; (void)ws_size;
  const float* x   = (const float*)d_in[0];
  const float* Wq  = (const float*)d_in[1];
  const float* bq  = (const float*)d_in[2];
  const float* Wk  = (const float*)d_in[3];
  const float* bk  = (const float*)d_in[4];
  const float* Wv  = (const float*)d_in[5];
  const float* bv  = (const float*)d_in[6];
  const float* Wo  = (const float*)d_in[7];
  const float* bo  = (const float*)d_in[8];
  const float* lng = (const float*)d_in[9];
  const float* lnb = (const float*)d_in[10];
  const float* ffg = (const float*)d_in[11];
  const float* ffb = (const float*)d_in[12];
  const float* W1  = (const float*)d_in[13];
  const float* b1  = (const float*)d_in[14];
  const float* W2  = (const float*)d_in[15];
  const float* b2  = (const float*)d_in[16];
  float* out = (float*)d_out;

  char* ws = (char*)d_ws;
  __bf16* h    = (__bf16*)(ws);
  __bf16* qb   = (__bf16*)(ws + (size_t)8 * 1024 * 1024);
  __bf16* kb   = (__bf16*)(ws + (size_t)16 * 1024 * 1024);
  __bf16* vT   = (__bf16*)(ws + (size_t)24 * 1024 * 1024);
  float*  x2   = (float*)(ws + (size_t)32 * 1024 * 1024);
  __bf16* fb   = (__bf16*)(ws + (size_t)48 * 1024 * 1024);
  __bf16* wqkv = (__bf16*)(ws + (size_t)56 * 1024 * 1024);
  __bf16* wo   = wqkv + 3 * 512 * 512;
  __bf16* w1t  = wo + 512 * 512;
  __bf16* w2t  = w1t + 512 * 2048;
  __bf16* g1   = (__bf16*)(ws);

  k_pre<<<12288 + 8192, 256, 0, stream>>>(Wq, Wk, Wv, Wo, W1, W2, wqkv, wo, w1t, w2t,
                                          x, lng, lnb, h);
  k_gemm_qkv<<<64 * 12, 512, 0, stream>>>(h, wqkv, bq, bk, bv, qb, kb, vT);
  k_attn<<<32 * 16, 512, 0, stream>>>(qb, kb, vT, h);  // o reuses h region
  k_gemm_oproj<<<128 * 8, 512, 0, stream>>>(h, wo, bo, x, x2);
  k_ln_ln<<<8192, 256, 0, stream>>>(x2, lng, lnb, ffg, ffb, fb);
  k_gemm_ffn1<<<64 * 16, 512, 0, stream>>>(fb, w1t, b1, g1);
  k_gemm_ffn2<<<128 * 8, 512, 0, stream>>>(g1, w2t, b2, x2, out);
}